// Round 4
// baseline (126.695 us; speedup 1.0000x reference)
//
#include <hip/hip_runtime.h>

constexpr int NB     = 64;    // batches
constexpr int NI     = 512;   // items per batch
constexpr int STK    = 6000;
constexpr int TILE_I = 64;    // i-values per block
constexpr int THREADS = 512;  // 8 waves
constexpr int ROWP   = 20;    // padded row stride (floats): 80B, 16B-aligned

__global__ __launch_bounds__(THREADS)
void stock_factor_kernel(const float* __restrict__ prices,
                         const float* __restrict__ emb_table,
                         const float* __restrict__ beta,
                         const int* __restrict__ stock_ids,
                         float* __restrict__ out)
{
    __shared__ float semb[NI][ROWP];
    __shared__ int   ssid[NI];

    const int b    = blockIdx.x;
    const int tile = blockIdx.y;
    const int tid  = threadIdx.x;
    const int lane = tid & 63;
    const int wave = tid >> 6;

    // Stage: all 512 embeddings of this batch + their ids into LDS.
    for (int r = tid; r < NI; r += THREADS) {
        const int sid = stock_ids[b * NI + r];
        ssid[r] = sid;
        const float4* src = (const float4*)(emb_table + (long long)sid * 16);
        float4 v0 = src[0], v1 = src[1], v2 = src[2], v3 = src[3];
        float4* dst = (float4*)(&semb[r][0]);
        dst[0] = v0; dst[1] = v1; dst[2] = v2; dst[3] = v3;
    }
    __syncthreads();

    // Each wave owns 8 consecutive i's, processed as 4 pairs.
    const int i0 = tile * TILE_I + wave * (TILE_I / 8);
    #pragma unroll
    for (int p = 0; p < 4; ++p) {
        const int iA = i0 + 2 * p;
        const int iB = iA + 1;
        const int sidA = ssid[iA];
        const int sidB = ssid[iB];
        const float* __restrict__ browA = beta + (long long)sidA * STK;
        const float* __restrict__ browB = beta + (long long)sidB * STK;

        float eiA[16], eiB[16];
        #pragma unroll
        for (int q = 0; q < 4; ++q) {
            float4 va = ((const float4*)(&semb[iA][0]))[q];
            float4 vb = ((const float4*)(&semb[iB][0]))[q];
            eiA[4*q+0] = va.x; eiA[4*q+1] = va.y; eiA[4*q+2] = va.z; eiA[4*q+3] = va.w;
            eiB[4*q+0] = vb.x; eiB[4*q+1] = vb.y; eiB[4*q+2] = vb.z; eiB[4*q+3] = vb.w;
        }

        float denomA = 0.f, numerA = 0.f;
        float denomB = 0.f, numerB = 0.f;
        #pragma unroll
        for (int k = 0; k < 8; ++k) {
            const int j = lane + 64 * k;
            const int sid_j = ssid[j];
            // Two gathers in flight per k (16 across the unrolled loop).
            const float bvA = browA[sid_j];
            const float bvB = browB[sid_j];

            const float4* ej4 = (const float4*)(&semb[j][0]);
            const float4 a0 = ej4[0], a1 = ej4[1], a2 = ej4[2], a3 = ej4[3];

            float dA, dB;
            dA  = eiA[0]  * a0.x; dB  = eiB[0]  * a0.x;
            dA += eiA[1]  * a0.y; dB += eiB[1]  * a0.y;
            dA += eiA[2]  * a0.z; dB += eiB[2]  * a0.z;
            dA += eiA[3]  * a0.w; dB += eiB[3]  * a0.w;
            dA += eiA[4]  * a1.x; dB += eiB[4]  * a1.x;
            dA += eiA[5]  * a1.y; dB += eiB[5]  * a1.y;
            dA += eiA[6]  * a1.z; dB += eiB[6]  * a1.z;
            dA += eiA[7]  * a1.w; dB += eiB[7]  * a1.w;
            dA += eiA[8]  * a2.x; dB += eiB[8]  * a2.x;
            dA += eiA[9]  * a2.y; dB += eiB[9]  * a2.y;
            dA += eiA[10] * a2.z; dB += eiB[10] * a2.z;
            dA += eiA[11] * a2.w; dB += eiB[11] * a2.w;
            dA += eiA[12] * a3.x; dB += eiB[12] * a3.x;
            dA += eiA[13] * a3.y; dB += eiB[13] * a3.y;
            dA += eiA[14] * a3.z; dB += eiB[14] * a3.z;
            dA += eiA[15] * a3.w; dB += eiB[15] * a3.w;

            float exA = __expf(dA);
            float exB = __expf(dB);
            if (j == iA) exA = 0.f;                       // diag: exp(-inf) = 0
            if (j == iB) exB = 0.f;
            denomA += exA;
            denomB += exB;
            numerA += (sid_j == sidA) ? 0.f : exA * bvA;  // beta zeroed on id match
            numerB += (sid_j == sidB) ? 0.f : exB * bvB;
        }

        // Wave-wide reduction of the 4 accumulators.
        #pragma unroll
        for (int off = 32; off; off >>= 1) {
            denomA += __shfl_xor(denomA, off);
            numerA += __shfl_xor(numerA, off);
            denomB += __shfl_xor(denomB, off);
            numerB += __shfl_xor(numerB, off);
        }

        if (lane == 0) {
            const float pA = prices[b * NI + iA];
            const float pB = prices[b * NI + iB];
            const float vA = pA * numerA / (denomA + 1e-8f);
            const float vB = pB * numerB / (denomB + 1e-8f);
            out[b * NI + iA] = vA;
            out[b * NI + iB] = vB;
            out[NB * NI + b * NI + iA] = vA - pA;
            out[NB * NI + b * NI + iB] = vB - pB;
        }
    }
}

extern "C" void kernel_launch(void* const* d_in, const int* in_sizes, int n_in,
                              void* d_out, int out_size, void* d_ws, size_t ws_size,
                              hipStream_t stream) {
    const float* prices     = (const float*)d_in[0];
    const float* emb_table  = (const float*)d_in[1];
    const float* beta       = (const float*)d_in[2];
    const int*   stock_ids  = (const int*)d_in[3];
    float* out = (float*)d_out;

    dim3 grid(NB, NI / TILE_I);
    stock_factor_kernel<<<grid, THREADS, 0, stream>>>(prices, emb_table, beta,
                                                      stock_ids, out);
}